// Round 4
// baseline (593.109 us; speedup 1.0000x reference)
//
#include <hip/hip_runtime.h>
#include <math.h>

#define B_  4096
#define T_  50
#define K_  32
#define D_  64
#define H_  256
#define HL_ 128
#define G4_ 512   // 4*HL

typedef __attribute__((ext_vector_type(8))) short bf16x8;
typedef __attribute__((ext_vector_type(4))) float f32x4;

__device__ __forceinline__ float fast_exp(float x){ return __expf(x); }
__device__ __forceinline__ float fast_rcp(float x){ return __builtin_amdgcn_rcpf(x); }
__device__ __forceinline__ float sigmoidf_(float x){ return fast_rcp(1.f + fast_exp(-x)); }
__device__ __forceinline__ float tanhf_(float x){ return 1.f - 2.f*fast_rcp(1.f + fast_exp(2.f*x)); }

__device__ __forceinline__ short f2bf(float f){
  union { float f; unsigned u; } v; v.f = f;
  unsigned r = v.u + 0x7FFFu + ((v.u >> 16) & 1u);   // round-to-nearest-even
  return (short)(r >> 16);
}
__device__ __forceinline__ float bf2f(short s){
  union { unsigned u; float f; } v; v.u = ((unsigned)(unsigned short)s) << 16;
  return v.f;
}

__device__ __forceinline__ float wave_reduce_sum(float v){
  #pragma unroll
  for (int off = 32; off; off >>= 1) v += __shfl_xor(v, off);
  return v;
}

// ---------------------------------------------------------------------------
// Kernel 1: per-student head. Unchanged (lstm is still the top dispatch).
// ---------------------------------------------------------------------------
#define KROW 72
#define PROW 40

__global__ __launch_bounds__(256) void head_kernel(
    const int* __restrict__ uididx, const int* __restrict__ kcodeidx,
    const int* __restrict__ kcode_len, const float* __restrict__ qidemb,
    const int* __restrict__ qid_len, const float* __restrict__ stuE,
    const float* __restrict__ knE,
    const float* __restrict__ T_W1, const float* __restrict__ T_b1,
    const float* __restrict__ T_W2, const float* __restrict__ T_b2,
    const float* __restrict__ A_W1, const float* __restrict__ A_b1,
    const float* __restrict__ A_W2, const float* __restrict__ A_b2,
    short* __restrict__ bvec, float* __restrict__ t_val, float* __restrict__ a_val)
{
  __shared__ __align__(16) short s_kemb[K_*KROW];
  __shared__ __align__(16) short s_kembT[D_*PROW];
  __shared__ __align__(16) short s_p[64*PROW];
  __shared__ float s_stu[D_];
  __shared__ float s_mast[K_];
  __shared__ float s_kmf[K_];
  __shared__ float s_mvec[D_];
  __shared__ float s_avec[D_];
  __shared__ float s_redT[4];
  __shared__ float s_redA[4];

  const int b    = blockIdx.x;
  const int tid  = threadIdx.x;
  const int lane = tid & 63;
  const int w    = tid >> 6;
  const int l15  = lane & 15;
  const int quad = lane >> 4;
  const int klen = kcode_len[b];
  const int qlen = qid_len[b];

  if (tid < D_) s_stu[tid] = stuE[uididx[b]*D_ + tid];
  #pragma unroll
  for (int i = tid; i < 512; i += 256){
    int k = i >> 4, f4 = i & 15;
    const float4 v = *(const float4*)&knE[(size_t)kcodeidx[b*K_ + k]*D_ + f4*4];
    short4 b4; b4.x = f2bf(v.x); b4.y = f2bf(v.y); b4.z = f2bf(v.z); b4.w = f2bf(v.w);
    *(short4*)&s_kemb[k*KROW + f4*4] = b4;
    int d = f4*4;
    s_kembT[(d+0)*PROW + k] = b4.x;
    s_kembT[(d+1)*PROW + k] = b4.y;
    s_kembT[(d+2)*PROW + k] = b4.z;
    s_kembT[(d+3)*PROW + k] = b4.w;
  }
  __syncthreads();

  // mastery: 8 lanes per k, bank-rotated
  {
    int k = tid >> 3, l8 = tid & 7;
    float s = 0.f;
    #pragma unroll
    for (int j = 0; j < 8; ++j){
      int d = l8 + 8*((j + k) & 7);
      s += s_stu[d] * bf2f(s_kemb[k*KROW + d]);
    }
    s += __shfl_xor(s, 1); s += __shfl_xor(s, 2); s += __shfl_xor(s, 4);
    if (l8 == 0){
      float valid = (k < klen) ? 1.f : 0.f;
      s_mast[k] = valid * sigmoidf_(s * 0.2f);
      s_kmf[k]  = valid;
    }
  }
  __syncthreads();

  if (tid < D_){
    float mv = 0.f, av = 0.f;
    #pragma unroll 4
    for (int k = 0; k < K_; ++k){
      float e = bf2f(s_kemb[k*KROW + tid]);
      mv += s_mast[k] * e;
      av += s_kmf[k]  * e;
    }
    s_mvec[tid] = mv; s_avec[tid] = av;
  }
  __syncthreads();

  // ---- attention via MFMA; q A-frags straight from global ----
  {
    const int qrow = w*16 + l15;
    bf16x8 aq[2];
    #pragma unroll
    for (int kt = 0; kt < 2; ++kt){
      if (qrow < qlen){
        const float4 v0 = *(const float4*)&qidemb[((size_t)b*T_ + qrow)*D_ + kt*32 + quad*8];
        const float4 v1 = *(const float4*)&qidemb[((size_t)b*T_ + qrow)*D_ + kt*32 + quad*8 + 4];
        aq[kt][0]=f2bf(v0.x); aq[kt][1]=f2bf(v0.y); aq[kt][2]=f2bf(v0.z); aq[kt][3]=f2bf(v0.w);
        aq[kt][4]=f2bf(v1.x); aq[kt][5]=f2bf(v1.y); aq[kt][6]=f2bf(v1.z); aq[kt][7]=f2bf(v1.w);
      } else {
        aq[kt][0]=0; aq[kt][1]=0; aq[kt][2]=0; aq[kt][3]=0;
        aq[kt][4]=0; aq[kt][5]=0; aq[kt][6]=0; aq[kt][7]=0;
      }
    }
    f32x4 zero = {0.f, 0.f, 0.f, 0.f};
    f32x4 accs[2] = {zero, zero};
    #pragma unroll
    for (int kt = 0; kt < 2; ++kt){
      #pragma unroll
      for (int nt = 0; nt < 2; ++nt){
        bf16x8 bk = *(const bf16x8*)&s_kemb[(nt*16 + l15)*KROW + kt*32 + quad*8];
        accs[nt] = __builtin_amdgcn_mfma_f32_16x16x32_bf16(aq[kt], bk, accs[nt], 0, 0, 0);
      }
    }
    #pragma unroll
    for (int r = 0; r < 4; ++r){
      float v0 = (l15      < klen) ? accs[0][r]*0.15f : -1e9f;
      float v1 = (l15 + 16 < klen) ? accs[1][r]*0.15f : -1e9f;
      float mx = fmaxf(v0, v1);
      #pragma unroll
      for (int off = 1; off < 16; off <<= 1) mx = fmaxf(mx, __shfl_xor(mx, off));
      float e0 = fast_exp(v0 - mx), e1 = fast_exp(v1 - mx);
      float sm = e0 + e1;
      #pragma unroll
      for (int off = 1; off < 16; off <<= 1) sm += __shfl_xor(sm, off);
      float inv = fast_rcp(sm);
      int row = w*16 + quad*4 + r;
      s_p[row*PROW + l15]      = f2bf(e0 * inv);
      s_p[row*PROW + 16 + l15] = f2bf(e1 * inv);
    }
    bf16x8 ap = *(const bf16x8*)&s_p[(w*16 + l15)*PROW + quad*8];
    #pragma unroll
    for (int nt = 0; nt < 4; ++nt){
      bf16x8 bv = *(const bf16x8*)&s_kembT[(nt*16 + l15)*PROW + quad*8];
      f32x4 acco = __builtin_amdgcn_mfma_f32_16x16x32_bf16(ap, bv, zero, 0, 0, 0);
      #pragma unroll
      for (int r = 0; r < 4; ++r){
        int t = w*16 + quad*4 + r;
        if (t < qlen) bvec[((size_t)b*T_ + t)*D_ + nt*16 + l15] = f2bf(acco[r]);
      }
    }
  }

  // ---- both DNNs interleaved ----
  {
    float accT = T_b1[tid];
    float accA = A_b1[tid];
    #pragma unroll 4
    for (int d = 0; d < D_; ++d){
      float mv = s_mvec[d], av = s_avec[d];
      accT += mv * T_W1[d*H_ + tid];
      accA += av * A_W1[d*H_ + tid];
    }
    float termT = tanhf_(accT) * T_W2[tid];
    float termA = tanhf_(accA) * A_W2[tid];
    termT = wave_reduce_sum(termT);
    termA = wave_reduce_sum(termA);
    if (lane == 0){ s_redT[w] = termT; s_redA[w] = termA; }
    __syncthreads();
    if (tid == 0){
      t_val[b] = s_redT[0] + s_redT[1] + s_redT[2] + s_redT[3] + T_b2[0];
      float v = s_redA[0] + s_redA[1] + s_redA[2] + s_redA[3] + A_b2[0];
      a_val[b] = 8.f * (sigmoidf_(fabsf(v)) - 0.5f);
    }
  }
}

// ---------------------------------------------------------------------------
// Kernel 2: MFMA LSTM, R15: TWO BARRIER GROUPS PER CU.
// Diagnosis after 3 neutral rounds: step = 3360 cyc vs ~800 cyc issue floor;
// OccupancyPercent pinned at 19.6% = exactly 1 block/CU -> every wave on the
// CU waits at the SAME barrier; 75% of the step is uncoverable stall.
// Fix: 8 students/block -> 512 blocks -> 2 independent blocks/CU
// (launch_bounds(512,4) pins VGPR<=128 so both fit). Block A's barrier
// stalls are filled by block B's issue (m114 mechanism).
// Padding avoidance: B-operand cols 8-15 DUPLICATE students 0-7
// (st8 = l15&7), so lane-pair (l15, l15+8) holds identical gate quadruples
// and each processes HALF the components (rb = (l15>>3)*2). Per-thread
// trans instrs 40 -> 20: per-SIMD trans issue stays ~640 cyc even at
// 4 waves/SIMD. MFMA/wave unchanged (24). Math per h-value bit-identical.
// ---------------------------------------------------------------------------
#define HROW 280   // shorts/row: h0(128)|h1(128)|pad(24)

__global__ __launch_bounds__(512, 4) void lstm_kernel(
    const short* __restrict__ bvec, const int* __restrict__ qid_len,
    const float* __restrict__ L_Wi, const float* __restrict__ L_Wh,
    const float* __restrict__ L_b,  const float* __restrict__ L_Wo,
    const float* __restrict__ L_bo, const float* __restrict__ t_val,
    const float* __restrict__ a_val, float* __restrict__ out)
{
  __shared__ __align__(16) short s_A[8*HROW];
  __shared__ int s_len[8];

  const int tid  = threadIdx.x;
  const int s0   = blockIdx.x * 8;
  const int w    = tid >> 6;
  const int lane = tid & 63;
  const int l15  = lane & 15;
  const int quad = lane >> 4;
  const int st8  = l15 & 7;          // real student owned by this thread
  const int rb   = (l15 >> 3) * 2;   // which 2 acc components this thread does

  // Weight fragments (MFMA A operand): col = g*128 + w*16 + l15 (FULL l15 —
  // A rows are the 16 weight cols), k = kt*32 + quad*8 + j.
  bf16x8 wf[4][6];
  f32x4  biasv4[4];   // per-component bias: col = g*128 + w*16 + quad*4 + r
  #pragma unroll
  for (int g = 0; g < 4; ++g){
    const int col = g*128 + w*16 + l15;
    #pragma unroll
    for (int r = 0; r < 4; ++r) biasv4[g][r] = L_b[g*128 + w*16 + quad*4 + r];
    #pragma unroll
    for (int kt = 0; kt < 6; ++kt){
      #pragma unroll
      for (int j = 0; j < 8; ++j){
        int k = kt*32 + quad*8 + j;
        float v = (k < D_) ? L_Wi[k*G4_ + col] : L_Wh[(k-D_)*G4_ + col];
        wf[g][kt][j] = f2bf(v);
      }
    }
  }

  for (int p = tid; p < 8*HROW; p += 512) s_A[p] = 0;
  if (tid < 8) s_len[tid] = qid_len[s0 + tid];
  __syncthreads();

  int maxlen = 0;
  #pragma unroll
  for (int i = 0; i < 8; ++i) maxlen = max(maxlen, s_len[i]);
  const int mylen = s_len[st8];
  float c_reg[2] = {0.f, 0.f};
  float h_reg[2] = {0.f, 0.f};

  // x fragments direct from global (bf16), double-buffered in registers.
  // B-operand col l15 carries student (l15&7): cols 8-15 duplicate 0-7.
  const short* gx = bvec + (size_t)(s0 + st8)*T_*D_ + quad*8;
  bf16x8 xA0 = *(const bf16x8*)(gx);
  bf16x8 xA1 = *(const bf16x8*)(gx + 32);
  bf16x8 xB0 = xA0, xB1 = xA1;
  if (1 < maxlen){ xB0 = *(const bf16x8*)(gx + D_); xB1 = *(const bf16x8*)(gx + D_ + 32); }
  __syncthreads();

#define MF(Aop, Bop, Cop) __builtin_amdgcn_mfma_f32_16x16x32_bf16((Aop), (Bop), (Cop), 0, 0, 0)

#define LSTM_STEP(TI, XB, XC0, XC1) do {                                       \
    const int hb_ = (XB) ^ 1;                                                  \
    const bf16x8 ah0 = *(const bf16x8*)&s_A[st8*HROW + hb_*128 +  0 + quad*8]; \
    const bf16x8 ah1 = *(const bf16x8*)&s_A[st8*HROW + hb_*128 + 32 + quad*8]; \
    const bf16x8 ah2 = *(const bf16x8*)&s_A[st8*HROW + hb_*128 + 64 + quad*8]; \
    const bf16x8 ah3 = *(const bf16x8*)&s_A[st8*HROW + hb_*128 + 96 + quad*8]; \
    f32x4 a0_ = biasv4[0], a1_ = biasv4[1], a2_ = biasv4[2], a3_ = biasv4[3];  \
    a0_ = MF(wf[0][0], XC0, a0_); a0_ = MF(wf[0][1], XC1, a0_);                \
    a1_ = MF(wf[1][0], XC0, a1_); a1_ = MF(wf[1][1], XC1, a1_);                \
    a2_ = MF(wf[2][0], XC0, a2_); a2_ = MF(wf[2][1], XC1, a2_);                \
    a3_ = MF(wf[3][0], XC0, a3_); a3_ = MF(wf[3][1], XC1, a3_);                \
    if ((TI) + 2 < maxlen){                                                    \
      XC0 = *(const bf16x8*)(gx + ((TI)+2)*D_);                                \
      XC1 = *(const bf16x8*)(gx + ((TI)+2)*D_ + 32);                           \
    }                                                                          \
    a0_ = MF(wf[0][2], ah0, a0_); a0_ = MF(wf[0][3], ah1, a0_);                \
    a0_ = MF(wf[0][4], ah2, a0_); a0_ = MF(wf[0][5], ah3, a0_);                \
    a1_ = MF(wf[1][2], ah0, a1_); a1_ = MF(wf[1][3], ah1, a1_);                \
    a1_ = MF(wf[1][4], ah2, a1_); a1_ = MF(wf[1][5], ah3, a1_);                \
    a2_ = MF(wf[2][2], ah0, a2_); a2_ = MF(wf[2][3], ah1, a2_);                \
    a2_ = MF(wf[2][4], ah2, a2_); a2_ = MF(wf[2][5], ah3, a2_);                \
    a3_ = MF(wf[3][2], ah0, a3_); a3_ = MF(wf[3][3], ah1, a3_);                \
    a3_ = MF(wf[3][4], ah2, a3_); a3_ = MF(wf[3][5], ah3, a3_);                \
    const bool upd_ = (TI) < mylen;                                            \
    _Pragma("unroll")                                                          \
    for (int k = 0; k < 2; ++k){                                               \
      const int r = rb + k;                                                    \
      float gi = a0_[r], gf = a1_[r], gg = a2_[r], go = a3_[r];                \
      float c2 = sigmoidf_(gf)*c_reg[k] + sigmoidf_(gi)*tanhf_(gg);            \
      float h2 = sigmoidf_(go)*tanhf_(c2);                                     \
      c_reg[k] = upd_ ? c2 : c_reg[k];                                         \
      h_reg[k] = upd_ ? h2 : h_reg[k];                                         \
    }                                                                          \
    unsigned hp_ = (unsigned)(unsigned short)f2bf(h_reg[0])                    \
                 | ((unsigned)(unsigned short)f2bf(h_reg[1]) << 16);           \
    *(unsigned*)&s_A[st8*HROW + (XB)*128 + w*16 + quad*4 + rb] = hp_;          \
    __syncthreads();                                                           \
  } while(0)

  int t = 0;
  for (; t + 1 < maxlen; t += 2){
    LSTM_STEP(t,   0, xA0, xA1);
    LSTM_STEP(t+1, 1, xB0, xB1);
  }
  if (t < maxlen) LSTM_STEP(t, 0, xA0, xA1);
#undef LSTM_STEP
#undef MF

  const int xbLast = (maxlen - 1) & 1;
  if (w < 8){
    const int s2 = w;
    float h0 = bf2f(s_A[s2*HROW + xbLast*128 + lane]);
    float h1 = bf2f(s_A[s2*HROW + xbLast*128 + 64 + lane]);
    float part = h0*L_Wo[lane] + h1*L_Wo[64+lane];
    part = wave_reduce_sum(part);
    if (lane == 0){
      float bb = 8.f * (sigmoidf_(part + L_bo[0]) - 0.5f);
      out[s0+s2] = sigmoidf_(a_val[s0+s2] * (t_val[s0+s2] - bb));
    }
  }
}

// ---------------------------------------------------------------------------
extern "C" void kernel_launch(void* const* d_in, const int* in_sizes, int n_in,
                              void* d_out, int out_size, void* d_ws, size_t ws_size,
                              hipStream_t stream)
{
  (void)in_sizes; (void)n_in; (void)out_size; (void)ws_size;
  const int*   uididx    = (const int*)  d_in[0];
  const int*   kcodeidx  = (const int*)  d_in[1];
  const int*   kcode_len = (const int*)  d_in[2];
  const float* qidemb    = (const float*)d_in[3];
  const int*   qid_len   = (const int*)  d_in[4];
  const float* stuE      = (const float*)d_in[5];
  const float* knE       = (const float*)d_in[6];
  const float* T_W1      = (const float*)d_in[7];
  const float* T_b1      = (const float*)d_in[8];
  const float* T_W2      = (const float*)d_in[9];
  const float* T_b2      = (const float*)d_in[10];
  const float* A_W1      = (const float*)d_in[11];
  const float* A_b1      = (const float*)d_in[12];
  const float* A_W2      = (const float*)d_in[13];
  const float* A_b2      = (const float*)d_in[14];
  const float* L_Wi      = (const float*)d_in[15];
  const float* L_Wh      = (const float*)d_in[16];
  const float* L_b       = (const float*)d_in[17];
  const float* L_Wo      = (const float*)d_in[18];
  const float* L_bo      = (const float*)d_in[19];
  float* out = (float*)d_out;

  short* bvec  = (short*)d_ws;                       // B*T*D bf16 = 26.2 MB
  float* t_val = (float*)(bvec + (size_t)B_*T_*D_);  // B floats
  float* a_val = t_val + B_;                         // B floats

  hipLaunchKernelGGL(head_kernel, dim3(B_), dim3(256), 0, stream,
    uididx, kcodeidx, kcode_len, qidemb, qid_len, stuE, knE,
    T_W1, T_b1, T_W2, T_b2, A_W1, A_b1, A_W2, A_b2,
    bvec, t_val, a_val);

  hipLaunchKernelGGL(lstm_kernel, dim3(B_/8), dim3(512), 0, stream,
    bvec, qid_len, L_Wi, L_Wh, L_b, L_Wo, L_bo, t_val, a_val, out);
}

// Round 5
// 250.664 us; speedup vs baseline: 2.3662x; 2.3662x over previous
//
#include <hip/hip_runtime.h>
#include <math.h>

#define B_  4096
#define T_  50
#define K_  32
#define D_  64
#define H_  256
#define HL_ 128
#define G4_ 512   // 4*HL

typedef __attribute__((ext_vector_type(8))) short bf16x8;
typedef __attribute__((ext_vector_type(4))) float f32x4;

__device__ __forceinline__ float fast_exp(float x){ return __expf(x); }
__device__ __forceinline__ float fast_rcp(float x){ return __builtin_amdgcn_rcpf(x); }
__device__ __forceinline__ float sigmoidf_(float x){ return fast_rcp(1.f + fast_exp(-x)); }
__device__ __forceinline__ float tanhf_(float x){ return 1.f - 2.f*fast_rcp(1.f + fast_exp(2.f*x)); }

__device__ __forceinline__ short f2bf(float f){
  union { float f; unsigned u; } v; v.f = f;
  unsigned r = v.u + 0x7FFFu + ((v.u >> 16) & 1u);   // round-to-nearest-even
  return (short)(r >> 16);
}
__device__ __forceinline__ float bf2f(short s){
  union { unsigned u; float f; } v; v.u = ((unsigned)(unsigned short)s) << 16;
  return v.f;
}

__device__ __forceinline__ float wave_reduce_sum(float v){
  #pragma unroll
  for (int off = 32; off; off >>= 1) v += __shfl_xor(v, off);
  return v;
}

// ---------------------------------------------------------------------------
// Kernel 1: per-student head. Unchanged (lstm is still the top dispatch).
// ---------------------------------------------------------------------------
#define KROW 72
#define PROW 40

__global__ __launch_bounds__(256) void head_kernel(
    const int* __restrict__ uididx, const int* __restrict__ kcodeidx,
    const int* __restrict__ kcode_len, const float* __restrict__ qidemb,
    const int* __restrict__ qid_len, const float* __restrict__ stuE,
    const float* __restrict__ knE,
    const float* __restrict__ T_W1, const float* __restrict__ T_b1,
    const float* __restrict__ T_W2, const float* __restrict__ T_b2,
    const float* __restrict__ A_W1, const float* __restrict__ A_b1,
    const float* __restrict__ A_W2, const float* __restrict__ A_b2,
    short* __restrict__ bvec, float* __restrict__ t_val, float* __restrict__ a_val)
{
  __shared__ __align__(16) short s_kemb[K_*KROW];
  __shared__ __align__(16) short s_kembT[D_*PROW];
  __shared__ __align__(16) short s_p[64*PROW];
  __shared__ float s_stu[D_];
  __shared__ float s_mast[K_];
  __shared__ float s_kmf[K_];
  __shared__ float s_mvec[D_];
  __shared__ float s_avec[D_];
  __shared__ float s_redT[4];
  __shared__ float s_redA[4];

  const int b    = blockIdx.x;
  const int tid  = threadIdx.x;
  const int lane = tid & 63;
  const int w    = tid >> 6;
  const int l15  = lane & 15;
  const int quad = lane >> 4;
  const int klen = kcode_len[b];
  const int qlen = qid_len[b];

  if (tid < D_) s_stu[tid] = stuE[uididx[b]*D_ + tid];
  #pragma unroll
  for (int i = tid; i < 512; i += 256){
    int k = i >> 4, f4 = i & 15;
    const float4 v = *(const float4*)&knE[(size_t)kcodeidx[b*K_ + k]*D_ + f4*4];
    short4 b4; b4.x = f2bf(v.x); b4.y = f2bf(v.y); b4.z = f2bf(v.z); b4.w = f2bf(v.w);
    *(short4*)&s_kemb[k*KROW + f4*4] = b4;
    int d = f4*4;
    s_kembT[(d+0)*PROW + k] = b4.x;
    s_kembT[(d+1)*PROW + k] = b4.y;
    s_kembT[(d+2)*PROW + k] = b4.z;
    s_kembT[(d+3)*PROW + k] = b4.w;
  }
  __syncthreads();

  // mastery: 8 lanes per k, bank-rotated
  {
    int k = tid >> 3, l8 = tid & 7;
    float s = 0.f;
    #pragma unroll
    for (int j = 0; j < 8; ++j){
      int d = l8 + 8*((j + k) & 7);
      s += s_stu[d] * bf2f(s_kemb[k*KROW + d]);
    }
    s += __shfl_xor(s, 1); s += __shfl_xor(s, 2); s += __shfl_xor(s, 4);
    if (l8 == 0){
      float valid = (k < klen) ? 1.f : 0.f;
      s_mast[k] = valid * sigmoidf_(s * 0.2f);
      s_kmf[k]  = valid;
    }
  }
  __syncthreads();

  if (tid < D_){
    float mv = 0.f, av = 0.f;
    #pragma unroll 4
    for (int k = 0; k < K_; ++k){
      float e = bf2f(s_kemb[k*KROW + tid]);
      mv += s_mast[k] * e;
      av += s_kmf[k]  * e;
    }
    s_mvec[tid] = mv; s_avec[tid] = av;
  }
  __syncthreads();

  // ---- attention via MFMA; q A-frags straight from global ----
  {
    const int qrow = w*16 + l15;
    bf16x8 aq[2];
    #pragma unroll
    for (int kt = 0; kt < 2; ++kt){
      if (qrow < qlen){
        const float4 v0 = *(const float4*)&qidemb[((size_t)b*T_ + qrow)*D_ + kt*32 + quad*8];
        const float4 v1 = *(const float4*)&qidemb[((size_t)b*T_ + qrow)*D_ + kt*32 + quad*8 + 4];
        aq[kt][0]=f2bf(v0.x); aq[kt][1]=f2bf(v0.y); aq[kt][2]=f2bf(v0.z); aq[kt][3]=f2bf(v0.w);
        aq[kt][4]=f2bf(v1.x); aq[kt][5]=f2bf(v1.y); aq[kt][6]=f2bf(v1.z); aq[kt][7]=f2bf(v1.w);
      } else {
        aq[kt][0]=0; aq[kt][1]=0; aq[kt][2]=0; aq[kt][3]=0;
        aq[kt][4]=0; aq[kt][5]=0; aq[kt][6]=0; aq[kt][7]=0;
      }
    }
    f32x4 zero = {0.f, 0.f, 0.f, 0.f};
    f32x4 accs[2] = {zero, zero};
    #pragma unroll
    for (int kt = 0; kt < 2; ++kt){
      #pragma unroll
      for (int nt = 0; nt < 2; ++nt){
        bf16x8 bk = *(const bf16x8*)&s_kemb[(nt*16 + l15)*KROW + kt*32 + quad*8];
        accs[nt] = __builtin_amdgcn_mfma_f32_16x16x32_bf16(aq[kt], bk, accs[nt], 0, 0, 0);
      }
    }
    #pragma unroll
    for (int r = 0; r < 4; ++r){
      float v0 = (l15      < klen) ? accs[0][r]*0.15f : -1e9f;
      float v1 = (l15 + 16 < klen) ? accs[1][r]*0.15f : -1e9f;
      float mx = fmaxf(v0, v1);
      #pragma unroll
      for (int off = 1; off < 16; off <<= 1) mx = fmaxf(mx, __shfl_xor(mx, off));
      float e0 = fast_exp(v0 - mx), e1 = fast_exp(v1 - mx);
      float sm = e0 + e1;
      #pragma unroll
      for (int off = 1; off < 16; off <<= 1) sm += __shfl_xor(sm, off);
      float inv = fast_rcp(sm);
      int row = w*16 + quad*4 + r;
      s_p[row*PROW + l15]      = f2bf(e0 * inv);
      s_p[row*PROW + 16 + l15] = f2bf(e1 * inv);
    }
    bf16x8 ap = *(const bf16x8*)&s_p[(w*16 + l15)*PROW + quad*8];
    #pragma unroll
    for (int nt = 0; nt < 4; ++nt){
      bf16x8 bv = *(const bf16x8*)&s_kembT[(nt*16 + l15)*PROW + quad*8];
      f32x4 acco = __builtin_amdgcn_mfma_f32_16x16x32_bf16(ap, bv, zero, 0, 0, 0);
      #pragma unroll
      for (int r = 0; r < 4; ++r){
        int t = w*16 + quad*4 + r;
        if (t < qlen) bvec[((size_t)b*T_ + t)*D_ + nt*16 + l15] = f2bf(acco[r]);
      }
    }
  }

  // ---- both DNNs interleaved ----
  {
    float accT = T_b1[tid];
    float accA = A_b1[tid];
    #pragma unroll 4
    for (int d = 0; d < D_; ++d){
      float mv = s_mvec[d], av = s_avec[d];
      accT += mv * T_W1[d*H_ + tid];
      accA += av * A_W1[d*H_ + tid];
    }
    float termT = tanhf_(accT) * T_W2[tid];
    float termA = tanhf_(accA) * A_W2[tid];
    termT = wave_reduce_sum(termT);
    termA = wave_reduce_sum(termA);
    if (lane == 0){ s_redT[w] = termT; s_redA[w] = termA; }
    __syncthreads();
    if (tid == 0){
      t_val[b] = s_redT[0] + s_redT[1] + s_redT[2] + s_redT[3] + T_b2[0];
      float v = s_redA[0] + s_redA[1] + s_redA[2] + s_redA[3] + A_b2[0];
      a_val[b] = 8.f * (sigmoidf_(fabsf(v)) - 0.5f);
    }
  }
}

// ---------------------------------------------------------------------------
// Kernel 2: MFMA LSTM, R16: R15 structure (8 students/block, duplicated
// B-columns, halved per-thread activations) with the CORRECT occupancy
// constraint. R4 post-mortem: __launch_bounds__(512,4) was treated as
// min-4-BLOCKS/CU -> 32 waves -> 64 VGPR cap -> weight fragments spilled to
// scratch (FETCH 13.8MB->1.1GB, 447us). Occupancy DID hit 43% — mechanism
// confirmed, implementation wrong. Fix: __launch_bounds__(512,2): 16 waves
// -> 128 VGPR cap = this kernel's natural allocation (R13 was 124-128,
// this structure has fewer live regs). 512 blocks -> 2 independent barrier
// groups per CU; block A's barrier stalls filled by block B's issue.
// ---------------------------------------------------------------------------
#define HROW 280   // shorts/row: h0(128)|h1(128)|pad(24)

__global__ __launch_bounds__(512, 2) void lstm_kernel(
    const short* __restrict__ bvec, const int* __restrict__ qid_len,
    const float* __restrict__ L_Wi, const float* __restrict__ L_Wh,
    const float* __restrict__ L_b,  const float* __restrict__ L_Wo,
    const float* __restrict__ L_bo, const float* __restrict__ t_val,
    const float* __restrict__ a_val, float* __restrict__ out)
{
  __shared__ __align__(16) short s_A[8*HROW];
  __shared__ int s_len[8];

  const int tid  = threadIdx.x;
  const int s0   = blockIdx.x * 8;
  const int w    = tid >> 6;
  const int lane = tid & 63;
  const int l15  = lane & 15;
  const int quad = lane >> 4;
  const int st8  = l15 & 7;          // real student owned by this thread
  const int rb   = (l15 >> 3) * 2;   // which 2 acc components this thread does

  // Weight fragments (MFMA A operand): col = g*128 + w*16 + l15,
  // k = kt*32 + quad*8 + j.
  bf16x8 wf[4][6];
  f32x4  biasv4[4];   // per-component bias: col = g*128 + w*16 + quad*4 + r
  #pragma unroll
  for (int g = 0; g < 4; ++g){
    const int col = g*128 + w*16 + l15;
    #pragma unroll
    for (int r = 0; r < 4; ++r) biasv4[g][r] = L_b[g*128 + w*16 + quad*4 + r];
    #pragma unroll
    for (int kt = 0; kt < 6; ++kt){
      #pragma unroll
      for (int j = 0; j < 8; ++j){
        int k = kt*32 + quad*8 + j;
        float v = (k < D_) ? L_Wi[k*G4_ + col] : L_Wh[(k-D_)*G4_ + col];
        wf[g][kt][j] = f2bf(v);
      }
    }
  }

  for (int p = tid; p < 8*HROW; p += 512) s_A[p] = 0;
  if (tid < 8) s_len[tid] = qid_len[s0 + tid];
  __syncthreads();

  int maxlen = 0;
  #pragma unroll
  for (int i = 0; i < 8; ++i) maxlen = max(maxlen, s_len[i]);
  const int mylen = s_len[st8];
  float c_reg[2] = {0.f, 0.f};
  float h_reg[2] = {0.f, 0.f};

  // x fragments direct from global (bf16), double-buffered in registers.
  // B-operand col l15 carries student (l15&7): cols 8-15 duplicate 0-7.
  const short* gx = bvec + (size_t)(s0 + st8)*T_*D_ + quad*8;
  bf16x8 xA0 = *(const bf16x8*)(gx);
  bf16x8 xA1 = *(const bf16x8*)(gx + 32);
  bf16x8 xB0 = xA0, xB1 = xA1;
  if (1 < maxlen){ xB0 = *(const bf16x8*)(gx + D_); xB1 = *(const bf16x8*)(gx + D_ + 32); }
  __syncthreads();

#define MF(Aop, Bop, Cop) __builtin_amdgcn_mfma_f32_16x16x32_bf16((Aop), (Bop), (Cop), 0, 0, 0)

#define LSTM_STEP(TI, XB, XC0, XC1) do {                                       \
    const int hb_ = (XB) ^ 1;                                                  \
    const bf16x8 ah0 = *(const bf16x8*)&s_A[st8*HROW + hb_*128 +  0 + quad*8]; \
    const bf16x8 ah1 = *(const bf16x8*)&s_A[st8*HROW + hb_*128 + 32 + quad*8]; \
    const bf16x8 ah2 = *(const bf16x8*)&s_A[st8*HROW + hb_*128 + 64 + quad*8]; \
    const bf16x8 ah3 = *(const bf16x8*)&s_A[st8*HROW + hb_*128 + 96 + quad*8]; \
    f32x4 a0_ = biasv4[0], a1_ = biasv4[1], a2_ = biasv4[2], a3_ = biasv4[3];  \
    a0_ = MF(wf[0][0], XC0, a0_); a0_ = MF(wf[0][1], XC1, a0_);                \
    a1_ = MF(wf[1][0], XC0, a1_); a1_ = MF(wf[1][1], XC1, a1_);                \
    a2_ = MF(wf[2][0], XC0, a2_); a2_ = MF(wf[2][1], XC1, a2_);                \
    a3_ = MF(wf[3][0], XC0, a3_); a3_ = MF(wf[3][1], XC1, a3_);                \
    if ((TI) + 2 < maxlen){                                                    \
      XC0 = *(const bf16x8*)(gx + ((TI)+2)*D_);                                \
      XC1 = *(const bf16x8*)(gx + ((TI)+2)*D_ + 32);                           \
    }                                                                          \
    a0_ = MF(wf[0][2], ah0, a0_); a0_ = MF(wf[0][3], ah1, a0_);                \
    a0_ = MF(wf[0][4], ah2, a0_); a0_ = MF(wf[0][5], ah3, a0_);                \
    a1_ = MF(wf[1][2], ah0, a1_); a1_ = MF(wf[1][3], ah1, a1_);                \
    a1_ = MF(wf[1][4], ah2, a1_); a1_ = MF(wf[1][5], ah3, a1_);                \
    a2_ = MF(wf[2][2], ah0, a2_); a2_ = MF(wf[2][3], ah1, a2_);                \
    a2_ = MF(wf[2][4], ah2, a2_); a2_ = MF(wf[2][5], ah3, a2_);                \
    a3_ = MF(wf[3][2], ah0, a3_); a3_ = MF(wf[3][3], ah1, a3_);                \
    a3_ = MF(wf[3][4], ah2, a3_); a3_ = MF(wf[3][5], ah3, a3_);                \
    const bool upd_ = (TI) < mylen;                                            \
    _Pragma("unroll")                                                          \
    for (int k = 0; k < 2; ++k){                                               \
      const int r = rb + k;                                                    \
      float gi = a0_[r], gf = a1_[r], gg = a2_[r], go = a3_[r];                \
      float c2 = sigmoidf_(gf)*c_reg[k] + sigmoidf_(gi)*tanhf_(gg);            \
      float h2 = sigmoidf_(go)*tanhf_(c2);                                     \
      c_reg[k] = upd_ ? c2 : c_reg[k];                                         \
      h_reg[k] = upd_ ? h2 : h_reg[k];                                         \
    }                                                                          \
    unsigned hp_ = (unsigned)(unsigned short)f2bf(h_reg[0])                    \
                 | ((unsigned)(unsigned short)f2bf(h_reg[1]) << 16);           \
    *(unsigned*)&s_A[st8*HROW + (XB)*128 + w*16 + quad*4 + rb] = hp_;          \
    __syncthreads();                                                           \
  } while(0)

  int t = 0;
  for (; t + 1 < maxlen; t += 2){
    LSTM_STEP(t,   0, xA0, xA1);
    LSTM_STEP(t+1, 1, xB0, xB1);
  }
  if (t < maxlen) LSTM_STEP(t, 0, xA0, xA1);
#undef LSTM_STEP
#undef MF

  const int xbLast = (maxlen - 1) & 1;
  if (w < 8){
    const int s2 = w;
    float h0 = bf2f(s_A[s2*HROW + xbLast*128 + lane]);
    float h1 = bf2f(s_A[s2*HROW + xbLast*128 + 64 + lane]);
    float part = h0*L_Wo[lane] + h1*L_Wo[64+lane];
    part = wave_reduce_sum(part);
    if (lane == 0){
      float bb = 8.f * (sigmoidf_(part + L_bo[0]) - 0.5f);
      out[s0+s2] = sigmoidf_(a_val[s0+s2] * (t_val[s0+s2] - bb));
    }
  }
}

// ---------------------------------------------------------------------------
extern "C" void kernel_launch(void* const* d_in, const int* in_sizes, int n_in,
                              void* d_out, int out_size, void* d_ws, size_t ws_size,
                              hipStream_t stream)
{
  (void)in_sizes; (void)n_in; (void)out_size; (void)ws_size;
  const int*   uididx    = (const int*)  d_in[0];
  const int*   kcodeidx  = (const int*)  d_in[1];
  const int*   kcode_len = (const int*)  d_in[2];
  const float* qidemb    = (const float*)d_in[3];
  const int*   qid_len   = (const int*)  d_in[4];
  const float* stuE      = (const float*)d_in[5];
  const float* knE       = (const float*)d_in[6];
  const float* T_W1      = (const float*)d_in[7];
  const float* T_b1      = (const float*)d_in[8];
  const float* T_W2      = (const float*)d_in[9];
  const float* T_b2      = (const float*)d_in[10];
  const float* A_W1      = (const float*)d_in[11];
  const float* A_b1      = (const float*)d_in[12];
  const float* A_W2      = (const float*)d_in[13];
  const float* A_b2      = (const float*)d_in[14];
  const float* L_Wi      = (const float*)d_in[15];
  const float* L_Wh      = (const float*)d_in[16];
  const float* L_b       = (const float*)d_in[17];
  const float* L_Wo      = (const float*)d_in[18];
  const float* L_bo      = (const float*)d_in[19];
  float* out = (float*)d_out;

  short* bvec  = (short*)d_ws;                       // B*T*D bf16 = 26.2 MB
  float* t_val = (float*)(bvec + (size_t)B_*T_*D_);  // B floats
  float* a_val = t_val + B_;                         // B floats

  hipLaunchKernelGGL(head_kernel, dim3(B_), dim3(256), 0, stream,
    uididx, kcodeidx, kcode_len, qidemb, qid_len, stuE, knE,
    T_W1, T_b1, T_W2, T_b2, A_W1, A_b1, A_W2, A_b2,
    bvec, t_val, a_val);

  hipLaunchKernelGGL(lstm_kernel, dim3(B_/8), dim3(512), 0, stream,
    bvec, qid_len, L_Wi, L_Wh, L_b, L_Wo, L_bo, t_val, a_val, out);
}

// Round 6
// 225.555 us; speedup vs baseline: 2.6296x; 1.1113x over previous
//
#include <hip/hip_runtime.h>
#include <math.h>

#define B_  4096
#define T_  50
#define K_  32
#define D_  64
#define H_  256
#define HL_ 128
#define G4_ 512   // 4*HL

typedef __attribute__((ext_vector_type(8))) short bf16x8;
typedef __attribute__((ext_vector_type(4))) float f32x4;

__device__ __forceinline__ float fast_exp(float x){ return __expf(x); }
__device__ __forceinline__ float fast_rcp(float x){ return __builtin_amdgcn_rcpf(x); }
__device__ __forceinline__ float sigmoidf_(float x){ return fast_rcp(1.f + fast_exp(-x)); }
__device__ __forceinline__ float tanhf_(float x){ return 1.f - 2.f*fast_rcp(1.f + fast_exp(2.f*x)); }

__device__ __forceinline__ short f2bf(float f){
  union { float f; unsigned u; } v; v.f = f;
  unsigned r = v.u + 0x7FFFu + ((v.u >> 16) & 1u);   // round-to-nearest-even
  return (short)(r >> 16);
}
__device__ __forceinline__ float bf2f(short s){
  union { unsigned u; float f; } v; v.u = ((unsigned)(unsigned short)s) << 16;
  return v.f;
}

__device__ __forceinline__ float wave_reduce_sum(float v){
  #pragma unroll
  for (int off = 32; off; off >>= 1) v += __shfl_xor(v, off);
  return v;
}

// ---------------------------------------------------------------------------
// Kernel 1: per-student head, R17: DNN phase REMOVED (moved to lstm prologue
// where 16 students/block amortize the T_W1/A_W1 L2 streams 16x: 512MB ->
// 32MB). head now just writes mvec/avec fp32 to workspace (bit-identical
// values to what the DNN consumed before). Everything else unchanged from
// the 221.6us-verified baseline.
// ---------------------------------------------------------------------------
#define KROW 72
#define PROW 40

__global__ __launch_bounds__(256) void head_kernel(
    const int* __restrict__ uididx, const int* __restrict__ kcodeidx,
    const int* __restrict__ kcode_len, const float* __restrict__ qidemb,
    const int* __restrict__ qid_len, const float* __restrict__ stuE,
    const float* __restrict__ knE,
    short* __restrict__ bvec, float* __restrict__ mvecG, float* __restrict__ avecG)
{
  __shared__ __align__(16) short s_kemb[K_*KROW];
  __shared__ __align__(16) short s_kembT[D_*PROW];
  __shared__ __align__(16) short s_p[64*PROW];
  __shared__ float s_stu[D_];
  __shared__ float s_mast[K_];
  __shared__ float s_kmf[K_];

  const int b    = blockIdx.x;
  const int tid  = threadIdx.x;
  const int lane = tid & 63;
  const int w    = tid >> 6;
  const int l15  = lane & 15;
  const int quad = lane >> 4;
  const int klen = kcode_len[b];
  const int qlen = qid_len[b];

  if (tid < D_) s_stu[tid] = stuE[uididx[b]*D_ + tid];
  #pragma unroll
  for (int i = tid; i < 512; i += 256){
    int k = i >> 4, f4 = i & 15;
    const float4 v = *(const float4*)&knE[(size_t)kcodeidx[b*K_ + k]*D_ + f4*4];
    short4 b4; b4.x = f2bf(v.x); b4.y = f2bf(v.y); b4.z = f2bf(v.z); b4.w = f2bf(v.w);
    *(short4*)&s_kemb[k*KROW + f4*4] = b4;
    int d = f4*4;
    s_kembT[(d+0)*PROW + k] = b4.x;
    s_kembT[(d+1)*PROW + k] = b4.y;
    s_kembT[(d+2)*PROW + k] = b4.z;
    s_kembT[(d+3)*PROW + k] = b4.w;
  }
  __syncthreads();

  // mastery: 8 lanes per k, bank-rotated
  {
    int k = tid >> 3, l8 = tid & 7;
    float s = 0.f;
    #pragma unroll
    for (int j = 0; j < 8; ++j){
      int d = l8 + 8*((j + k) & 7);
      s += s_stu[d] * bf2f(s_kemb[k*KROW + d]);
    }
    s += __shfl_xor(s, 1); s += __shfl_xor(s, 2); s += __shfl_xor(s, 4);
    if (l8 == 0){
      float valid = (k < klen) ? 1.f : 0.f;
      s_mast[k] = valid * sigmoidf_(s * 0.2f);
      s_kmf[k]  = valid;
    }
  }
  __syncthreads();

  if (tid < D_){
    float mv = 0.f, av = 0.f;
    #pragma unroll 4
    for (int k = 0; k < K_; ++k){
      float e = bf2f(s_kemb[k*KROW + tid]);
      mv += s_mast[k] * e;
      av += s_kmf[k]  * e;
    }
    mvecG[(size_t)b*D_ + tid] = mv;
    avecG[(size_t)b*D_ + tid] = av;
  }
  __syncthreads();

  // ---- attention via MFMA; q A-frags straight from global ----
  {
    const int qrow = w*16 + l15;
    bf16x8 aq[2];
    #pragma unroll
    for (int kt = 0; kt < 2; ++kt){
      if (qrow < qlen){
        const float4 v0 = *(const float4*)&qidemb[((size_t)b*T_ + qrow)*D_ + kt*32 + quad*8];
        const float4 v1 = *(const float4*)&qidemb[((size_t)b*T_ + qrow)*D_ + kt*32 + quad*8 + 4];
        aq[kt][0]=f2bf(v0.x); aq[kt][1]=f2bf(v0.y); aq[kt][2]=f2bf(v0.z); aq[kt][3]=f2bf(v0.w);
        aq[kt][4]=f2bf(v1.x); aq[kt][5]=f2bf(v1.y); aq[kt][6]=f2bf(v1.z); aq[kt][7]=f2bf(v1.w);
      } else {
        aq[kt][0]=0; aq[kt][1]=0; aq[kt][2]=0; aq[kt][3]=0;
        aq[kt][4]=0; aq[kt][5]=0; aq[kt][6]=0; aq[kt][7]=0;
      }
    }
    f32x4 zero = {0.f, 0.f, 0.f, 0.f};
    f32x4 accs[2] = {zero, zero};
    #pragma unroll
    for (int kt = 0; kt < 2; ++kt){
      #pragma unroll
      for (int nt = 0; nt < 2; ++nt){
        bf16x8 bk = *(const bf16x8*)&s_kemb[(nt*16 + l15)*KROW + kt*32 + quad*8];
        accs[nt] = __builtin_amdgcn_mfma_f32_16x16x32_bf16(aq[kt], bk, accs[nt], 0, 0, 0);
      }
    }
    #pragma unroll
    for (int r = 0; r < 4; ++r){
      float v0 = (l15      < klen) ? accs[0][r]*0.15f : -1e9f;
      float v1 = (l15 + 16 < klen) ? accs[1][r]*0.15f : -1e9f;
      float mx = fmaxf(v0, v1);
      #pragma unroll
      for (int off = 1; off < 16; off <<= 1) mx = fmaxf(mx, __shfl_xor(mx, off));
      float e0 = fast_exp(v0 - mx), e1 = fast_exp(v1 - mx);
      float sm = e0 + e1;
      #pragma unroll
      for (int off = 1; off < 16; off <<= 1) sm += __shfl_xor(sm, off);
      float inv = fast_rcp(sm);
      int row = w*16 + quad*4 + r;
      s_p[row*PROW + l15]      = f2bf(e0 * inv);
      s_p[row*PROW + 16 + l15] = f2bf(e1 * inv);
    }
    bf16x8 ap = *(const bf16x8*)&s_p[(w*16 + l15)*PROW + quad*8];
    #pragma unroll
    for (int nt = 0; nt < 4; ++nt){
      bf16x8 bv = *(const bf16x8*)&s_kembT[(nt*16 + l15)*PROW + quad*8];
      f32x4 acco = __builtin_amdgcn_mfma_f32_16x16x32_bf16(ap, bv, zero, 0, 0, 0);
      #pragma unroll
      for (int r = 0; r < 4; ++r){
        int t = w*16 + quad*4 + r;
        if (t < qlen) bvec[((size_t)b*T_ + t)*D_ + nt*16 + l15] = f2bf(acco[r]);
      }
    }
  }
}

// ---------------------------------------------------------------------------
// Kernel 2: MFMA LSTM, R17 = verified-best R13 structure (16 students/block,
// x-from-global double-buffered in regs, gate-major MFMA with interleaved
// activations, one __syncthreads/step — 66.5us steady) + the two head-DNNs
// folded into the PROLOGUE (thread = (student, 8 H-cols); W1 read once per
// block from L2 -> 16x amortized; t/a kept in LDS, never round-trip HBM).
// PLATEAU NOTE (R12-R16): per-step issue-count cuts, barrier de-drain, and
// 2-blocks/CU all neutral-or-worse; weights (96 VGPR x 8 waves) pin ONE
// barrier group per CU — ~66us is structural for this decomposition.
// ---------------------------------------------------------------------------
#define HROW 280   // shorts/row: h0(128)|h1(128)|pad(24)

__global__ __launch_bounds__(512) void lstm_kernel(
    const short* __restrict__ bvec, const int* __restrict__ qid_len,
    const float* __restrict__ L_Wi, const float* __restrict__ L_Wh,
    const float* __restrict__ L_b,  const float* __restrict__ L_Wo,
    const float* __restrict__ L_bo,
    const float* __restrict__ T_W1, const float* __restrict__ T_b1,
    const float* __restrict__ T_W2, const float* __restrict__ T_b2,
    const float* __restrict__ A_W1, const float* __restrict__ A_b1,
    const float* __restrict__ A_W2, const float* __restrict__ A_b2,
    const float* __restrict__ mvecG, const float* __restrict__ avecG,
    float* __restrict__ out)
{
  __shared__ __align__(16) short s_A[16*HROW];
  __shared__ int s_len[16];
  __shared__ float s_tv[16];
  __shared__ float s_av[16];

  const int tid  = threadIdx.x;
  const int s0   = blockIdx.x * 16;
  const int w    = tid >> 6;
  const int lane = tid & 63;
  const int l15  = lane & 15;
  const int quad = lane >> 4;

  // ---- folded DNNs: thread = (student sI, 8 cols c0..c0+7) ----
  {
    const int sI = tid >> 5;
    const int c0 = (tid & 31) * 8;
    const float* mv = mvecG + (size_t)(s0 + sI)*D_;
    const float* av = avecG + (size_t)(s0 + sI)*D_;
    float accT[8], accA[8];
    #pragma unroll
    for (int j = 0; j < 8; ++j){ accT[j] = T_b1[c0+j]; accA[j] = A_b1[c0+j]; }
    for (int d = 0; d < D_; ++d){
      const float m = mv[d], a = av[d];
      const float4 wT0 = *(const float4*)&T_W1[d*H_ + c0];
      const float4 wT1 = *(const float4*)&T_W1[d*H_ + c0 + 4];
      const float4 wA0 = *(const float4*)&A_W1[d*H_ + c0];
      const float4 wA1 = *(const float4*)&A_W1[d*H_ + c0 + 4];
      accT[0] += m*wT0.x; accT[1] += m*wT0.y; accT[2] += m*wT0.z; accT[3] += m*wT0.w;
      accT[4] += m*wT1.x; accT[5] += m*wT1.y; accT[6] += m*wT1.z; accT[7] += m*wT1.w;
      accA[0] += a*wA0.x; accA[1] += a*wA0.y; accA[2] += a*wA0.z; accA[3] += a*wA0.w;
      accA[4] += a*wA1.x; accA[5] += a*wA1.y; accA[6] += a*wA1.z; accA[7] += a*wA1.w;
    }
    float tT = 0.f, tA = 0.f;
    #pragma unroll
    for (int j = 0; j < 8; ++j){
      tT += tanhf_(accT[j]) * T_W2[c0+j];
      tA += tanhf_(accA[j]) * A_W2[c0+j];
    }
    #pragma unroll
    for (int off = 1; off < 32; off <<= 1){
      tT += __shfl_xor(tT, off);
      tA += __shfl_xor(tA, off);
    }
    if ((lane & 31) == 0){
      s_tv[sI] = tT + T_b2[0];
      s_av[sI] = 8.f * (sigmoidf_(fabsf(tA + A_b2[0])) - 0.5f);
    }
  }

  // Weight fragments (MFMA A operand): col = g*128 + w*16 + l15,
  // k = kt*32 + quad*8 + j.
  bf16x8 wf[4][6];
  f32x4  biasv4[4];   // per-component bias: col = g*128 + w*16 + quad*4 + r
  #pragma unroll
  for (int g = 0; g < 4; ++g){
    const int col = g*128 + w*16 + l15;
    #pragma unroll
    for (int r = 0; r < 4; ++r) biasv4[g][r] = L_b[g*128 + w*16 + quad*4 + r];
    #pragma unroll
    for (int kt = 0; kt < 6; ++kt){
      #pragma unroll
      for (int j = 0; j < 8; ++j){
        int k = kt*32 + quad*8 + j;
        float v = (k < D_) ? L_Wi[k*G4_ + col] : L_Wh[(k-D_)*G4_ + col];
        wf[g][kt][j] = f2bf(v);
      }
    }
  }

  for (int p = tid; p < 16*HROW; p += 512) s_A[p] = 0;
  if (tid < 16) s_len[tid] = qid_len[s0 + tid];
  __syncthreads();

  int maxlen = 0;
  #pragma unroll
  for (int i = 0; i < 16; ++i) maxlen = max(maxlen, s_len[i]);
  const int mylen = s_len[l15];           // one mask per thread (student l15)
  float c_reg[4] = {0.f,0.f,0.f,0.f};
  float h_reg[4] = {0.f,0.f,0.f,0.f};

  // x fragments direct from global (bf16), double-buffered in registers.
  const short* gx = bvec + (size_t)(s0 + l15)*T_*D_ + quad*8;
  bf16x8 xA0 = *(const bf16x8*)(gx);
  bf16x8 xA1 = *(const bf16x8*)(gx + 32);
  bf16x8 xB0 = xA0, xB1 = xA1;
  if (1 < maxlen){ xB0 = *(const bf16x8*)(gx + D_); xB1 = *(const bf16x8*)(gx + D_ + 32); }
  __syncthreads();

#define MF(Aop, Bop, Cop) __builtin_amdgcn_mfma_f32_16x16x32_bf16((Aop), (Bop), (Cop), 0, 0, 0)

#define LSTM_STEP(TI, XB, XC0, XC1) do {                                       \
    const int hb_ = (XB) ^ 1;                                                  \
    const bf16x8 ah0 = *(const bf16x8*)&s_A[l15*HROW + hb_*128 +  0 + quad*8]; \
    const bf16x8 ah1 = *(const bf16x8*)&s_A[l15*HROW + hb_*128 + 32 + quad*8]; \
    const bf16x8 ah2 = *(const bf16x8*)&s_A[l15*HROW + hb_*128 + 64 + quad*8]; \
    const bf16x8 ah3 = *(const bf16x8*)&s_A[l15*HROW + hb_*128 + 96 + quad*8]; \
    f32x4 a0_ = biasv4[0], a1_ = biasv4[1], a2_ = biasv4[2], a3_ = biasv4[3];  \
    a0_ = MF(wf[0][0], XC0, a0_); a0_ = MF(wf[0][1], XC1, a0_);                \
    a1_ = MF(wf[1][0], XC0, a1_); a1_ = MF(wf[1][1], XC1, a1_);                \
    a2_ = MF(wf[2][0], XC0, a2_); a2_ = MF(wf[2][1], XC1, a2_);                \
    a3_ = MF(wf[3][0], XC0, a3_); a3_ = MF(wf[3][1], XC1, a3_);                \
    if ((TI) + 2 < maxlen){                                                    \
      XC0 = *(const bf16x8*)(gx + ((TI)+2)*D_);                                \
      XC1 = *(const bf16x8*)(gx + ((TI)+2)*D_ + 32);                           \
    }                                                                          \
    a0_ = MF(wf[0][2], ah0, a0_); a0_ = MF(wf[0][3], ah1, a0_);                \
    a0_ = MF(wf[0][4], ah2, a0_); a0_ = MF(wf[0][5], ah3, a0_);                \
    a1_ = MF(wf[1][2], ah0, a1_); a1_ = MF(wf[1][3], ah1, a1_);                \
    a1_ = MF(wf[1][4], ah2, a1_); a1_ = MF(wf[1][5], ah3, a1_);                \
    float si_[4], sf_[4], tg_[4], so_[4];                                      \
    _Pragma("unroll") for (int r = 0; r < 4; ++r) si_[r] = sigmoidf_(a0_[r]);  \
    a2_ = MF(wf[2][2], ah0, a2_); a2_ = MF(wf[2][3], ah1, a2_);                \
    a2_ = MF(wf[2][4], ah2, a2_); a2_ = MF(wf[2][5], ah3, a2_);                \
    _Pragma("unroll") for (int r = 0; r < 4; ++r) sf_[r] = sigmoidf_(a1_[r]);  \
    a3_ = MF(wf[3][2], ah0, a3_); a3_ = MF(wf[3][3], ah1, a3_);                \
    a3_ = MF(wf[3][4], ah2, a3_); a3_ = MF(wf[3][5], ah3, a3_);                \
    _Pragma("unroll") for (int r = 0; r < 4; ++r) tg_[r] = tanhf_(a2_[r]);     \
    _Pragma("unroll") for (int r = 0; r < 4; ++r) so_[r] = sigmoidf_(a3_[r]);  \
    const bool upd_ = (TI) < mylen;                                            \
    _Pragma("unroll")                                                          \
    for (int r = 0; r < 4; ++r){                                               \
      float c2 = sf_[r]*c_reg[r] + si_[r]*tg_[r];                              \
      float h2 = so_[r]*tanhf_(c2);                                            \
      c_reg[r] = upd_ ? c2 : c_reg[r];                                         \
      h_reg[r] = upd_ ? h2 : h_reg[r];                                         \
    }                                                                          \
    uint2 hp_;                                                                 \
    hp_.x = (unsigned)(unsigned short)f2bf(h_reg[0])                           \
          | ((unsigned)(unsigned short)f2bf(h_reg[1]) << 16);                  \
    hp_.y = (unsigned)(unsigned short)f2bf(h_reg[2])                           \
          | ((unsigned)(unsigned short)f2bf(h_reg[3]) << 16);                  \
    *(uint2*)&s_A[l15*HROW + (XB)*128 + w*16 + quad*4] = hp_;                  \
    __syncthreads();                                                           \
  } while(0)

  int t = 0;
  for (; t + 1 < maxlen; t += 2){
    LSTM_STEP(t,   0, xA0, xA1);
    LSTM_STEP(t+1, 1, xB0, xB1);
  }
  if (t < maxlen) LSTM_STEP(t, 0, xA0, xA1);
#undef LSTM_STEP
#undef MF

  const int xbLast = (maxlen - 1) & 1;
  for (int s2 = w; s2 < 16; s2 += 8){
    float h0 = bf2f(s_A[s2*HROW + xbLast*128 + lane]);
    float h1 = bf2f(s_A[s2*HROW + xbLast*128 + 64 + lane]);
    float part = h0*L_Wo[lane] + h1*L_Wo[64+lane];
    part = wave_reduce_sum(part);
    if (lane == 0){
      float bb = 8.f * (sigmoidf_(part + L_bo[0]) - 0.5f);
      out[s0+s2] = sigmoidf_(s_av[s2] * (s_tv[s2] - bb));
    }
  }
}

// ---------------------------------------------------------------------------
extern "C" void kernel_launch(void* const* d_in, const int* in_sizes, int n_in,
                              void* d_out, int out_size, void* d_ws, size_t ws_size,
                              hipStream_t stream)
{
  (void)in_sizes; (void)n_in; (void)out_size; (void)ws_size;
  const int*   uididx    = (const int*)  d_in[0];
  const int*   kcodeidx  = (const int*)  d_in[1];
  const int*   kcode_len = (const int*)  d_in[2];
  const float* qidemb    = (const float*)d_in[3];
  const int*   qid_len   = (const int*)  d_in[4];
  const float* stuE      = (const float*)d_in[5];
  const float* knE       = (const float*)d_in[6];
  const float* T_W1      = (const float*)d_in[7];
  const float* T_b1      = (const float*)d_in[8];
  const float* T_W2      = (const float*)d_in[9];
  const float* T_b2      = (const float*)d_in[10];
  const float* A_W1      = (const float*)d_in[11];
  const float* A_b1      = (const float*)d_in[12];
  const float* A_W2      = (const float*)d_in[13];
  const float* A_b2      = (const float*)d_in[14];
  const float* L_Wi      = (const float*)d_in[15];
  const float* L_Wh      = (const float*)d_in[16];
  const float* L_b       = (const float*)d_in[17];
  const float* L_Wo      = (const float*)d_in[18];
  const float* L_bo      = (const float*)d_in[19];
  float* out = (float*)d_out;

  short* bvec  = (short*)d_ws;                        // B*T*D bf16 = 26.2 MB
  float* mvecG = (float*)(bvec + (size_t)B_*T_*D_);   // B*D f32 = 1 MB
  float* avecG = mvecG + (size_t)B_*D_;               // B*D f32 = 1 MB

  hipLaunchKernelGGL(head_kernel, dim3(B_), dim3(256), 0, stream,
    uididx, kcodeidx, kcode_len, qidemb, qid_len, stuE, knE,
    bvec, mvecG, avecG);

  hipLaunchKernelGGL(lstm_kernel, dim3(B_/16), dim3(512), 0, stream,
    bvec, qid_len, L_Wi, L_Wh, L_b, L_Wo, L_bo,
    T_W1, T_b1, T_W2, T_b2, A_W1, A_b1, A_W2, A_b2,
    mvecG, avecG, out);
}